// Round 5
// baseline (731.410 us; speedup 1.0000x reference)
//
#include <hip/hip_runtime.h>
#include <hip/hip_bf16.h>

// Problem constants (fixed by reference): N=262144 rows, D=64, K=512 codes.
#define N_ROWS 262144
#define DIM 64
#define KC 512

// d_out layout — FLOAT32 (verified passing):
//   out[0]                      = loss
//   out[1 .. 1+N*D)             = quantized [N,64] row-major
//   out[1+N*D .. 1+N*D+N)       = float(encoding_indices)
//
// Indices must match np.argmin of the reference's FLOAT32 distance array.
// We replicate numpy's f32 numerics exactly:
//   x_sq, e_sq : numpy pairwise sum, n=64 => 8-accumulator striped scheme
//   dot        : sequential fused-FMA chain, ascending j (OpenBLAS microkernel)
//   d          : fl( fl(x_sq + e_sq_k) - 2*dot_k ), contraction off
//   argmin     : strict <, first-min-wins (k ascending)
//
// R4 post-mortem: hand-rolled s_load_dwordx16 pipeline -> WRONG indices.
// Root cause: inline-asm SMEM loads write SGPRs asynchronously, but the
// compiler treats asm outputs as defined at the asm point; any tuple copy
// between issue and the lgkmcnt wait reads stale registers. Unsound. Reverted.
//
// R3 counter re-read: WRITE=67MB (pure output), FETCH=34.5MB => NO scratch
// traffic, yet VGPR_Count=40. xr lives in AGPRs (gfx950 unified file spill):
// v_accvgpr_read + v_fmac per FMA = the observed 2.3x VALU inflation.
// launch_bounds(256,2) only sets MIN waves/EU; the backend still maximizes
// occupancy and AGPR-parks xr. R5 lever (sole change vs the passing R3
// kernel): amdgpu_waves_per_eu(2,2) clamps the occupancy TARGET to 2
// waves/EU => 256-VGPR budget => xr stays in architectural VGPRs.

// numpy pairwise sum of squares for n=64 (scalar path, PW_BLOCKSIZE=128):
//   r[j] = sum_{i ≡ j mod 8} fl(a_i*a_i), sequential in i;
//   res  = ((r0+r1)+(r2+r3)) + ((r4+r5)+(r6+r7))
__device__ __forceinline__ float np_sumsq64(const float* a) {
#pragma clang fp contract(off)
    float r[8];
#pragma unroll
    for (int j = 0; j < 8; ++j) r[j] = a[j] * a[j];
#pragma unroll
    for (int i = 8; i < 64; i += 8)
#pragma unroll
        for (int j = 0; j < 8; ++j) r[j] = r[j] + a[i + j] * a[i + j];
    return ((r[0] + r[1]) + (r[2] + r[3])) + ((r[4] + r[5]) + (r[6] + r[7]));
}

// ---- kernel 1: e_sq_k with numpy bit-exact summation ----
__global__ void esq_kernel(const float* __restrict__ cb, float* __restrict__ esq) {
    int k = blockIdx.x * blockDim.x + threadIdx.x;
    if (k < KC) esq[k] = np_sumsq64(cb + k * DIM);
}

// ---- kernel 2: main VQ — one thread per row ----
__global__ __launch_bounds__(256)
__attribute__((amdgpu_waves_per_eu(2, 2)))   // pin occupancy target: 256-VGPR budget
void vq_kernel(
    const float* __restrict__ x, const float* __restrict__ cb,
    const float* __restrict__ esq, float* __restrict__ out,
    float* __restrict__ loss_acc)
{
    const int row  = blockIdx.x * 256 + threadIdx.x;
    const int lane = threadIdx.x & 63;

    // Row into 64 VGPRs (16x float4, 256B-aligned).
    float xr[DIM];
    const float4* xv = reinterpret_cast<const float4*>(x + (size_t)row * DIM);
#pragma unroll
    for (int j = 0; j < DIM / 4; ++j) {
        float4 v = xv[j];
        xr[4 * j + 0] = v.x; xr[4 * j + 1] = v.y;
        xr[4 * j + 2] = v.z; xr[4 * j + 3] = v.w;
    }
    // Pin row elements to VGPR class (blocks load-sinking / AGPR-parking at
    // this point). With the 256-VGPR budget they should now stay put.
#pragma unroll
    for (int j = 0; j < DIM; ++j) asm volatile("" : "+v"(xr[j]));

    // numpy-exact ||x||^2.
    const float xsq = np_sumsq64(xr);

    // Replicated reference distance, argmin first-min-wins, k ascending.
    // k-unroll x2: two independent single-accumulator sequential fused-FMA
    // chains (each bit-identical to the reference's OpenBLAS microkernel).
    // 2 chains x 4-cyc FMA latency / 2-cyc wave64 issue => one wave alone
    // saturates the VALU; 2 waves/EU is plenty.
    float best = 3.4e38f;
    int bidx = 0;
#pragma unroll 1
    for (int k = 0; k < KC; k += 2) {
        const float* e = cb + (size_t)k * DIM;   // wave-uniform address
        float dot0 = 0.f, dot1 = 0.f;
#pragma unroll
        for (int j = 0; j < DIM; ++j) {
            dot0 = fmaf(xr[j], e[j      ], dot0);
            dot1 = fmaf(xr[j], e[DIM + j], dot1);
        }
        float d0, d1;
        {
#pragma clang fp contract(off)
            d0 = (xsq + esq[k + 0]) - 2.0f * dot0;  // 2*dot exact; each op rounds
            d1 = (xsq + esq[k + 1]) - 2.0f * dot1;
        }
        // strict <, ascending k: first-min-wins preserved.
        if (d0 < best) { best = d0; bidx = k + 0; }
        if (d1 < best) { best = d1; bidx = k + 1; }
    }

    // ---- wave-cooperative coalesced epilogue (R3-proven: WRITE 310->67MB) ----
    const size_t wave_row0 = (size_t)row - lane;
#pragma unroll 4
    for (int l = 0; l < 64; ++l) {
        const int idx = __shfl(bidx, l, 64);
        const float v = cb[(size_t)idx * DIM + lane];   // coalesced 256B read (L2-hot)
        out[1 + (wave_row0 + l) * DIM + lane] = v;      // coalesced 256B write
    }

    out[1 + (size_t)N_ROWS * DIM + row] = (float)bidx;  // coalesced

    // loss contribution: ||x - e||^2 = d_best (noise ~1e-5, threshold ~2%)
    float lrow = best;
#pragma unroll
    for (int off = 32; off > 0; off >>= 1) lrow += __shfl_down(lrow, off, 64);
    if (lane == 0) atomicAdd(loss_acc, lrow);
}

// ---- kernel 3: finalize loss ----
__global__ void fin_kernel(const float* __restrict__ loss_acc,
                           float* __restrict__ out) {
    if (threadIdx.x == 0) {
        float mean_sq = (*loss_acc) / (float)((size_t)N_ROWS * DIM);
        out[0] = 1.25f * mean_sq;  // q_loss + COMMITMENT_COST * e_loss
    }
}

extern "C" void kernel_launch(void* const* d_in, const int* in_sizes, int n_in,
                              void* d_out, int out_size, void* d_ws, size_t ws_size,
                              hipStream_t stream) {
    const float* x  = (const float*)d_in[0];
    const float* cb = (const float*)d_in[1];
    float* out = (float*)d_out;

    float* loss_acc = (float*)d_ws;                 // 4 B accumulator
    float* esq      = (float*)((char*)d_ws + 256);  // 512 floats

    hipMemsetAsync(d_ws, 0, 4, stream);             // zero loss accumulator
    esq_kernel<<<2, 256, 0, stream>>>(cb, esq);
    vq_kernel<<<N_ROWS / 256, 256, 0, stream>>>(x, cb, esq, out, loss_acc);
    fin_kernel<<<1, 64, 0, stream>>>(loss_acc, out);
}

// Round 6
// 448.693 us; speedup vs baseline: 1.6301x; 1.6301x over previous
//
#include <hip/hip_runtime.h>
#include <hip/hip_bf16.h>

// Problem constants (fixed by reference): N=262144 rows, D=64, K=512 codes.
#define N_ROWS 262144
#define DIM 64
#define KC 512

// d_out layout — FLOAT32 (verified passing):
//   out[0]                      = loss
//   out[1 .. 1+N*D)             = quantized [N,64] row-major
//   out[1+N*D .. 1+N*D+N)       = float(encoding_indices)
//
// Numerics replicated exactly (indices must match np.argmin of f32 dists):
//   x_sq, e_sq : numpy pairwise sum, n=64 => 8-accumulator striped scheme
//   dot        : sequential fused-FMA chain, ascending j (OpenBLAS kernel)
//   d          : fl( fl(x_sq + e_sq_k) - 2*dot_k ), contraction off
//   argmin     : strict <, first-min-wins (k ascending)
//
// R5 post-mortem: VGPR=88 (xr resident) yet VALU busy-time unchanged at
// ~247us (2.26x the 109us FMA floor) => the inflation is compiler-emitted
// per-FMA data movement around the e[j] loads (s->v movs / vector addr
// math), NOT AGPR copies. Also: occupancy is grid-capped at 4 waves/SIMD
// (4096 waves / 1024 SIMDs); R5's (2,2) clamp halved that => 649us.
//
// R6: take the compiler out of the inner loop. Each 16-float chunk is ONE
// self-contained asm block: s_load_dwordx16 x2 into FIXED sregs s[68:99],
// full lgkmcnt(0) drain, then 32 interleaved v_fmac (dot0/dot1, dep
// distance = 4 cyc = FMA latency). No SGPR value crosses an asm boundary
// (R4's unsoundness); full-drain waits make compiler SMEM loads (esq)
// harmless. waves_per_eu(4,4) = the grid's exact occupancy, 128-VGPR
// budget => no AGPR parking of xr (whose residency the asm's "v" inputs
// force at every use).

// 2 fused FMAs: chain0 (code k) from SA, chain1 (code k+1) from SB.
#define FM(SA, SB, XI) \
    "v_fmac_f32 %[d0], " SA ", %[" XI "]\n\t" \
    "v_fmac_f32 %[d1], " SB ", %[" XI "]\n\t"

// One 16-float chunk of both codes: load + drain + 32 sequential fused FMAs.
// All fixed-register (s68-s99) usage is INTERNAL to this single asm block.
#define DO_CHUNK(P) do {                                                     \
    const unsigned long long baseA = cbk + (unsigned)(4 * (P));              \
    const unsigned long long baseB = baseA + 256ull;                         \
    asm volatile(                                                            \
        "s_load_dwordx16 s[68:83], %[ba], 0x0\n\t"                           \
        "s_load_dwordx16 s[84:99], %[bb], 0x0\n\t"                           \
        "s_waitcnt lgkmcnt(0)\n\t"                                           \
        FM("s68","s84","x0")  FM("s69","s85","x1")                           \
        FM("s70","s86","x2")  FM("s71","s87","x3")                           \
        FM("s72","s88","x4")  FM("s73","s89","x5")                           \
        FM("s74","s90","x6")  FM("s75","s91","x7")                           \
        FM("s76","s92","x8")  FM("s77","s93","x9")                           \
        FM("s78","s94","x10") FM("s79","s95","x11")                          \
        FM("s80","s96","x12") FM("s81","s97","x13")                          \
        FM("s82","s98","x14") FM("s83","s99","x15")                          \
        : [d0]"+v"(dot0), [d1]"+v"(dot1)                                     \
        : [ba]"s"(baseA), [bb]"s"(baseB),                                    \
          [x0]"v"(xr[(P)+0]),  [x1]"v"(xr[(P)+1]),                           \
          [x2]"v"(xr[(P)+2]),  [x3]"v"(xr[(P)+3]),                           \
          [x4]"v"(xr[(P)+4]),  [x5]"v"(xr[(P)+5]),                           \
          [x6]"v"(xr[(P)+6]),  [x7]"v"(xr[(P)+7]),                           \
          [x8]"v"(xr[(P)+8]),  [x9]"v"(xr[(P)+9]),                           \
          [x10]"v"(xr[(P)+10]), [x11]"v"(xr[(P)+11]),                        \
          [x12]"v"(xr[(P)+12]), [x13]"v"(xr[(P)+13]),                        \
          [x14]"v"(xr[(P)+14]), [x15]"v"(xr[(P)+15])                         \
        : "s68","s69","s70","s71","s72","s73","s74","s75",                   \
          "s76","s77","s78","s79","s80","s81","s82","s83",                   \
          "s84","s85","s86","s87","s88","s89","s90","s91",                   \
          "s92","s93","s94","s95","s96","s97","s98","s99");                  \
} while (0)

// numpy pairwise sum of squares for n=64 (scalar path, PW_BLOCKSIZE=128).
__device__ __forceinline__ float np_sumsq64(const float* a) {
#pragma clang fp contract(off)
    float r[8];
#pragma unroll
    for (int j = 0; j < 8; ++j) r[j] = a[j] * a[j];
#pragma unroll
    for (int i = 8; i < 64; i += 8)
#pragma unroll
        for (int j = 0; j < 8; ++j) r[j] = r[j] + a[i + j] * a[i + j];
    return ((r[0] + r[1]) + (r[2] + r[3])) + ((r[4] + r[5]) + (r[6] + r[7]));
}

// ---- kernel 1: e_sq_k with numpy bit-exact summation ----
__global__ void esq_kernel(const float* __restrict__ cb, float* __restrict__ esq) {
    int k = blockIdx.x * blockDim.x + threadIdx.x;
    if (k < KC) esq[k] = np_sumsq64(cb + k * DIM);
}

// ---- kernel 2: main VQ — one thread per row ----
__global__ __launch_bounds__(256)
__attribute__((amdgpu_waves_per_eu(4, 4)))   // = grid occupancy; 128-VGPR budget
void vq_kernel(
    const float* __restrict__ x, const float* __restrict__ cb,
    const float* __restrict__ esq, float* __restrict__ out,
    float* __restrict__ loss_acc)
{
    const int row  = blockIdx.x * 256 + threadIdx.x;
    const int lane = threadIdx.x & 63;

    // Row into 64 VGPRs (16x float4, 256B-aligned).
    float xr[DIM];
    const float4* xv = reinterpret_cast<const float4*>(x + (size_t)row * DIM);
#pragma unroll
    for (int j = 0; j < DIM / 4; ++j) {
        float4 v = xv[j];
        xr[4 * j + 0] = v.x; xr[4 * j + 1] = v.y;
        xr[4 * j + 2] = v.z; xr[4 * j + 3] = v.w;
    }

    // numpy-exact ||x||^2.
    const float xsq = np_sumsq64(xr);

    const unsigned long long cbu = (unsigned long long)cb;

    float best = 3.4e38f;
    int bidx = 0;
#pragma unroll 1
    for (int k = 0; k < KC; k += 2) {
        const unsigned long long cbk = cbu + (unsigned long long)((unsigned)k * 256u);
        float dot0 = 0.f, dot1 = 0.f;
        DO_CHUNK(0);
        DO_CHUNK(16);
        DO_CHUNK(32);
        DO_CHUNK(48);
        float d0, d1;
        {
#pragma clang fp contract(off)
            d0 = (xsq + esq[k + 0]) - 2.0f * dot0;  // 2*dot exact; each op rounds
            d1 = (xsq + esq[k + 1]) - 2.0f * dot1;
        }
        // strict <, ascending k: first-min-wins preserved.
        if (d0 < best) { best = d0; bidx = k + 0; }
        if (d1 < best) { best = d1; bidx = k + 1; }
    }

    // ---- wave-cooperative coalesced epilogue (R3-proven: WRITE 310->67MB) ----
    const size_t wave_row0 = (size_t)row - lane;
#pragma unroll 4
    for (int l = 0; l < 64; ++l) {
        const int idx = __shfl(bidx, l, 64);
        const float v = cb[(size_t)idx * DIM + lane];   // coalesced 256B read (L2-hot)
        out[1 + (wave_row0 + l) * DIM + lane] = v;      // coalesced 256B write
    }

    out[1 + (size_t)N_ROWS * DIM + row] = (float)bidx;  // coalesced

    // loss contribution: ||x - e||^2 = d_best (noise ~1e-5, threshold ~2%)
    float lrow = best;
#pragma unroll
    for (int off = 32; off > 0; off >>= 1) lrow += __shfl_down(lrow, off, 64);
    if (lane == 0) atomicAdd(loss_acc, lrow);
}

// ---- kernel 3: finalize loss ----
__global__ void fin_kernel(const float* __restrict__ loss_acc,
                           float* __restrict__ out) {
    if (threadIdx.x == 0) {
        float mean_sq = (*loss_acc) / (float)((size_t)N_ROWS * DIM);
        out[0] = 1.25f * mean_sq;  // q_loss + COMMITMENT_COST * e_loss
    }
}

extern "C" void kernel_launch(void* const* d_in, const int* in_sizes, int n_in,
                              void* d_out, int out_size, void* d_ws, size_t ws_size,
                              hipStream_t stream) {
    const float* x  = (const float*)d_in[0];
    const float* cb = (const float*)d_in[1];
    float* out = (float*)d_out;

    float* loss_acc = (float*)d_ws;                 // 4 B accumulator
    float* esq      = (float*)((char*)d_ws + 256);  // 512 floats

    hipMemsetAsync(d_ws, 0, 4, stream);             // zero loss accumulator
    esq_kernel<<<2, 256, 0, stream>>>(cb, esq);
    vq_kernel<<<N_ROWS / 256, 256, 0, stream>>>(x, cb, esq, out, loss_acc);
    fin_kernel<<<1, 64, 0, stream>>>(loss_acc, out);
}

// Round 7
// 386.716 us; speedup vs baseline: 1.8913x; 1.1603x over previous
//
#include <hip/hip_runtime.h>
#include <hip/hip_bf16.h>

// Problem constants (fixed by reference): N=262144 rows, D=64, K=512 codes.
#define N_ROWS 262144
#define DIM 64
#define KC 512
#define BLK 1024                       // 16 waves/block, 1 block/CU (LDS-capped)
#define LDS_FLOATS (KC * DIM + KC)     // codebook + esq = 33280 floats = 133120 B

// d_out layout — FLOAT32 (verified passing):
//   out[0]                      = loss
//   out[1 .. 1+N*D)             = quantized [N,64] row-major
//   out[1+N*D .. 1+N*D+N)       = float(encoding_indices)
//
// Numerics replicated exactly (indices must match np.argmin of f32 dists):
//   x_sq, e_sq : numpy pairwise sum, n=64 => 8-accumulator striped scheme
//   dot        : sequential fused-FMA chain, ascending j (OpenBLAS kernel)
//   d          : fl( fl(x_sq + e_sq_k) - 2*dot_k ), contraction off
//   argmin     : strict <, first-min-wins (k ascending)
//
// R6 post-mortem: pure-asm inner loop (128 v_fmac + 2 s_load_dwordx16 +
// full drain per 2 codes) ran at the SAME ~382us / ~256us VALU busy-time
// as the compiler versions (R3: 253us, R5: 247us). Instruction stream was
// provably minimal => the wall is the scalar path itself: (a) s_load
// returns out-of-order so counted lgkmcnt waits are unsafe -> mandatory
// full drains (1024/thread) with sL1-thrash latency, and/or (b) v_fmac
// with SGPR source at reduced rate. Either way: leave the scalar path.
//
// R7: codebook + esq staged in LDS (130KB of the 160KB/CU). One
// 1024-thread block per CU (grid=256): 16 waves = 4/SIMD, same TLP as
// before. Inner loop: ds_read_b128 BROADCAST (wave-uniform address ->
// conflict-free; DS returns IN ORDER so compiler counted-lgkm pipelining
// is safe) + all-VGPR v_fmac at full 2-cyc rate. DS demand 32 b128/iter
// (<=384 cyc) overlaps under 512 VALU cyc/iter.

// numpy pairwise sum of squares for n=64 (scalar path, PW_BLOCKSIZE=128).
__device__ __forceinline__ float np_sumsq64(const float* a) {
#pragma clang fp contract(off)
    float r[8];
#pragma unroll
    for (int j = 0; j < 8; ++j) r[j] = a[j] * a[j];
#pragma unroll
    for (int i = 8; i < 64; i += 8)
#pragma unroll
        for (int j = 0; j < 8; ++j) r[j] = r[j] + a[i + j] * a[i + j];
    return ((r[0] + r[1]) + (r[2] + r[3])) + ((r[4] + r[5]) + (r[6] + r[7]));
}

// ---- kernel 1: e_sq_k with numpy bit-exact summation ----
__global__ void esq_kernel(const float* __restrict__ cb, float* __restrict__ esq) {
    int k = blockIdx.x * blockDim.x + threadIdx.x;
    if (k < KC) esq[k] = np_sumsq64(cb + k * DIM);
}

// ---- kernel 2: main VQ — one thread per row, codebook in LDS ----
__global__ __launch_bounds__(BLK)
__attribute__((amdgpu_waves_per_eu(4, 4)))   // exactly the grid occupancy; 128-VGPR budget
void vq_kernel(
    const float* __restrict__ x, const float* __restrict__ cb,
    const float* __restrict__ esq_g, float* __restrict__ out,
    float* __restrict__ loss_acc)
{
    extern __shared__ float smem[];
    float* cbs  = smem;             // [512*64] codebook, k-major (same layout as global)
    float* esql = smem + KC * DIM;  // [512]

    const int tid  = threadIdx.x;
    const int lane = tid & 63;
    const int row  = blockIdx.x * BLK + tid;

    // ---- cooperative stage: 128KB codebook + 2KB esq, fully coalesced ----
    {
        const float4* g4 = reinterpret_cast<const float4*>(cb);
        float4*       s4 = reinterpret_cast<float4*>(cbs);
#pragma unroll
        for (int i = 0; i < (KC * DIM / 4) / BLK; ++i)   // 8 iters
            s4[tid + i * BLK] = g4[tid + i * BLK];
        if (tid < KC) esql[tid] = esq_g[tid];
    }

    // Row into 64 VGPRs (16x float4, 256B-aligned) — overlaps staging latency.
    float xr[DIM];
    const float4* xv = reinterpret_cast<const float4*>(x + (size_t)row * DIM);
#pragma unroll
    for (int j = 0; j < DIM / 4; ++j) {
        float4 v = xv[j];
        xr[4 * j + 0] = v.x; xr[4 * j + 1] = v.y;
        xr[4 * j + 2] = v.z; xr[4 * j + 3] = v.w;
    }

    // numpy-exact ||x||^2.
    const float xsq = np_sumsq64(xr);

    __syncthreads();   // staging complete

    // Replicated reference distance, argmin first-min-wins, k ascending.
    // Two codes per iter = two independent sequential fused-FMA chains
    // (dep distance 4 cyc = FMA latency). e-values via LDS broadcast
    // (float4 -> ds_read_b128, wave-uniform addr, conflict-free, in-order
    // returns => compiler pipelines with counted lgkmcnt).
    float best = 3.4e38f;
    int bidx = 0;
#pragma unroll 1
    for (int k = 0; k < KC; k += 2) {
        const float4* ea = reinterpret_cast<const float4*>(cbs + k * DIM);
        const float4* eb = ea + DIM / 4;
        float dot0 = 0.f, dot1 = 0.f;
#pragma unroll
        for (int c = 0; c < DIM / 4; ++c) {
            const float4 a = ea[c];
            const float4 b = eb[c];
            dot0 = fmaf(xr[4 * c + 0], a.x, dot0);
            dot1 = fmaf(xr[4 * c + 0], b.x, dot1);
            dot0 = fmaf(xr[4 * c + 1], a.y, dot0);
            dot1 = fmaf(xr[4 * c + 1], b.y, dot1);
            dot0 = fmaf(xr[4 * c + 2], a.z, dot0);
            dot1 = fmaf(xr[4 * c + 2], b.z, dot1);
            dot0 = fmaf(xr[4 * c + 3], a.w, dot0);
            dot1 = fmaf(xr[4 * c + 3], b.w, dot1);
        }
        float d0, d1;
        {
#pragma clang fp contract(off)
            d0 = (xsq + esql[k + 0]) - 2.0f * dot0;  // 2*dot exact; each op rounds
            d1 = (xsq + esql[k + 1]) - 2.0f * dot1;
        }
        // strict <, ascending k: first-min-wins preserved.
        if (d0 < best) { best = d0; bidx = k + 0; }
        if (d1 < best) { best = d1; bidx = k + 1; }
    }

    // ---- wave-cooperative coalesced epilogue (R3-proven) ----
    // Gather quantized rows from LDS: lane l reads cbs[idx*64 + l] ->
    // banks l%32, 2-way aliasing = free. One 256B coalesced store per row.
    const size_t wave_row0 = (size_t)row - lane;
#pragma unroll 4
    for (int l = 0; l < 64; ++l) {
        const int idx = __shfl(bidx, l, 64);
        const float v = cbs[idx * DIM + lane];
        out[1 + (wave_row0 + l) * DIM + lane] = v;
    }

    out[1 + (size_t)N_ROWS * DIM + row] = (float)bidx;  // coalesced

    // loss contribution: ||x - e||^2 = d_best (noise ~1e-5, threshold ~2%)
    float lrow = best;
#pragma unroll
    for (int off = 32; off > 0; off >>= 1) lrow += __shfl_down(lrow, off, 64);
    if (lane == 0) atomicAdd(loss_acc, lrow);
}

// ---- kernel 3: finalize loss ----
__global__ void fin_kernel(const float* __restrict__ loss_acc,
                           float* __restrict__ out) {
    if (threadIdx.x == 0) {
        float mean_sq = (*loss_acc) / (float)((size_t)N_ROWS * DIM);
        out[0] = 1.25f * mean_sq;  // q_loss + COMMITMENT_COST * e_loss
    }
}

extern "C" void kernel_launch(void* const* d_in, const int* in_sizes, int n_in,
                              void* d_out, int out_size, void* d_ws, size_t ws_size,
                              hipStream_t stream) {
    const float* x  = (const float*)d_in[0];
    const float* cb = (const float*)d_in[1];
    float* out = (float*)d_out;

    float* loss_acc = (float*)d_ws;                 // 4 B accumulator
    float* esq      = (float*)((char*)d_ws + 256);  // 512 floats

    hipMemsetAsync(d_ws, 0, 4, stream);             // zero loss accumulator
    esq_kernel<<<2, 256, 0, stream>>>(cb, esq);
    vq_kernel<<<N_ROWS / BLK, BLK, LDS_FLOATS * sizeof(float), stream>>>(
        x, cb, esq, out, loss_acc);
    fin_kernel<<<1, 64, 0, stream>>>(loss_acc, out);
}

// Round 8
// 341.945 us; speedup vs baseline: 2.1390x; 1.1309x over previous
//
#include <hip/hip_runtime.h>
#include <hip/hip_bf16.h>

// Problem constants (fixed by reference): N=262144 rows, D=64, K=512 codes.
#define N_ROWS 262144
#define DIM 64
#define KC 512
#define BLK 512                        // threads/block; 8 waves = 2/SIMD, 1 block/CU
#define RPT 2                          // rows per thread
#define LDS_FLOATS (KC * DIM + KC)     // codebook + esq = 33280 floats = 133120 B

// d_out layout — FLOAT32 (verified passing):
//   out[0]                      = loss
//   out[1 .. 1+N*D)             = quantized [N,64] row-major
//   out[1+N*D .. 1+N*D+N)       = float(encoding_indices)
//
// Numerics replicated exactly (indices must match np.argmin of f32 dists):
//   x_sq, e_sq : numpy pairwise sum, n=64 => 8-accumulator striped scheme
//   dot        : sequential fused-FMA chain, ascending j (OpenBLAS kernel)
//   d          : fl( fl(x_sq + e_sq_k) - 2*dot_k ), contraction off
//   argmin     : strict <, first-min-wins (k ascending)
//
// R7 post-mortem: LDS codebook: 382->330us, VALUBusy 82%, conflicts 0.
// Remaining wall = LDS delivery + VALU issue poorly overlapped: each
// uniform ds_read_b128 delivers 16B to 64 lanes (~4cyc LDS pipe) but feeds
// only 4 FMAs (4B per FMA) => per-CU LDS demand ~218us vs VALU ~124us.
// R8: TWO ROWS PER THREAD. Each e-read now feeds 8 FMAs (2B/FMA): LDS
// demand halves; distance/argmin/loop overhead amortizes 2x. FMA issue
// unchanged (true floor ~109-164us). 512-thr blocks, 256 blocks = 1/CU,
// 2 waves/SIMD; 4 indep FMA chains x 2 waves = 8 chains/SIMD covers FMA
// latency (LDS reads are in-order and compiler-pipelined, unlike R5/R6's
// out-of-order SMEM which forced full drains). waves_per_eu(2,2) => 256
// VGPR budget for xr0[64]+xr1[64]+temps (~160).

// numpy pairwise sum of squares for n=64 (scalar path, PW_BLOCKSIZE=128).
__device__ __forceinline__ float np_sumsq64(const float* a) {
#pragma clang fp contract(off)
    float r[8];
#pragma unroll
    for (int j = 0; j < 8; ++j) r[j] = a[j] * a[j];
#pragma unroll
    for (int i = 8; i < 64; i += 8)
#pragma unroll
        for (int j = 0; j < 8; ++j) r[j] = r[j] + a[i + j] * a[i + j];
    return ((r[0] + r[1]) + (r[2] + r[3])) + ((r[4] + r[5]) + (r[6] + r[7]));
}

// ---- kernel 1: e_sq_k with numpy bit-exact summation ----
__global__ void esq_kernel(const float* __restrict__ cb, float* __restrict__ esq) {
    int k = blockIdx.x * blockDim.x + threadIdx.x;
    if (k < KC) esq[k] = np_sumsq64(cb + k * DIM);
}

// ---- kernel 2: main VQ — TWO rows per thread, codebook in LDS ----
__global__ __launch_bounds__(BLK)
__attribute__((amdgpu_waves_per_eu(2, 2)))   // grid-exact occupancy; 256-VGPR budget
void vq_kernel(
    const float* __restrict__ x, const float* __restrict__ cb,
    const float* __restrict__ esq_g, float* __restrict__ out,
    float* __restrict__ loss_acc)
{
    extern __shared__ float smem[];
    float* cbs  = smem;             // [512*64] codebook, k-major (global layout)
    float* esql = smem + KC * DIM;  // [512]

    const int tid  = threadIdx.x;
    const int lane = tid & 63;
    const int row0 = blockIdx.x * (BLK * RPT) + tid;   // rows row0 and row0+BLK
    const int row1 = row0 + BLK;

    // ---- cooperative stage: 128KB codebook + 2KB esq, fully coalesced ----
    {
        const float4* g4 = reinterpret_cast<const float4*>(cb);
        float4*       s4 = reinterpret_cast<float4*>(cbs);
#pragma unroll
        for (int i = 0; i < (KC * DIM / 4) / BLK; ++i)   // 16 iters
            s4[tid + i * BLK] = g4[tid + i * BLK];
        if (tid < KC) esql[tid] = esq_g[tid];
    }

    // Two rows into 128 VGPRs — overlaps staging latency.
    float xr0[DIM], xr1[DIM];
    {
        const float4* xv0 = reinterpret_cast<const float4*>(x + (size_t)row0 * DIM);
        const float4* xv1 = reinterpret_cast<const float4*>(x + (size_t)row1 * DIM);
#pragma unroll
        for (int j = 0; j < DIM / 4; ++j) {
            float4 v0 = xv0[j], v1 = xv1[j];
            xr0[4 * j + 0] = v0.x; xr0[4 * j + 1] = v0.y;
            xr0[4 * j + 2] = v0.z; xr0[4 * j + 3] = v0.w;
            xr1[4 * j + 0] = v1.x; xr1[4 * j + 1] = v1.y;
            xr1[4 * j + 2] = v1.z; xr1[4 * j + 3] = v1.w;
        }
    }

    // numpy-exact ||x||^2 per row.
    const float xsq0 = np_sumsq64(xr0);
    const float xsq1 = np_sumsq64(xr1);

    __syncthreads();   // staging complete

    // 2 codes x 2 rows per iter = 4 independent sequential fused-FMA chains.
    // Each 16B LDS broadcast read feeds 8 FMAs (was 4).
    float best0 = 3.4e38f, best1 = 3.4e38f;
    int bidx0 = 0, bidx1 = 0;
#pragma unroll 1
    for (int k = 0; k < KC; k += 2) {
        const float4* ea = reinterpret_cast<const float4*>(cbs + k * DIM);
        const float4* eb = ea + DIM / 4;
        float dot00 = 0.f, dot01 = 0.f, dot10 = 0.f, dot11 = 0.f;
#pragma unroll
        for (int c = 0; c < DIM / 4; ++c) {
            const float4 a = ea[c];
            const float4 b = eb[c];
            dot00 = fmaf(xr0[4 * c + 0], a.x, dot00);
            dot01 = fmaf(xr0[4 * c + 0], b.x, dot01);
            dot10 = fmaf(xr1[4 * c + 0], a.x, dot10);
            dot11 = fmaf(xr1[4 * c + 0], b.x, dot11);
            dot00 = fmaf(xr0[4 * c + 1], a.y, dot00);
            dot01 = fmaf(xr0[4 * c + 1], b.y, dot01);
            dot10 = fmaf(xr1[4 * c + 1], a.y, dot10);
            dot11 = fmaf(xr1[4 * c + 1], b.y, dot11);
            dot00 = fmaf(xr0[4 * c + 2], a.z, dot00);
            dot01 = fmaf(xr0[4 * c + 2], b.z, dot01);
            dot10 = fmaf(xr1[4 * c + 2], a.z, dot10);
            dot11 = fmaf(xr1[4 * c + 2], b.z, dot11);
            dot00 = fmaf(xr0[4 * c + 3], a.w, dot00);
            dot01 = fmaf(xr0[4 * c + 3], b.w, dot01);
            dot10 = fmaf(xr1[4 * c + 3], a.w, dot10);
            dot11 = fmaf(xr1[4 * c + 3], b.w, dot11);
        }
        float d00, d01, d10, d11;
        {
#pragma clang fp contract(off)
            const float e0 = esql[k + 0], e1 = esql[k + 1];
            d00 = (xsq0 + e0) - 2.0f * dot00;  // 2*dot exact; each op rounds
            d01 = (xsq0 + e1) - 2.0f * dot01;
            d10 = (xsq1 + e0) - 2.0f * dot10;
            d11 = (xsq1 + e1) - 2.0f * dot11;
        }
        // strict <, ascending k: first-min-wins preserved (per row).
        if (d00 < best0) { best0 = d00; bidx0 = k + 0; }
        if (d01 < best0) { best0 = d01; bidx0 = k + 1; }
        if (d10 < best1) { best1 = d10; bidx1 = k + 0; }
        if (d11 < best1) { best1 = d11; bidx1 = k + 1; }
    }

    // ---- wave-cooperative coalesced epilogue (R3-proven), once per row-set ----
    // LDS gather: lane l reads cbs[idx*64 + l] -> 2-way bank aliasing = free.
    const size_t wave_row0 = (size_t)row0 - lane;
#pragma unroll 4
    for (int l = 0; l < 64; ++l) {
        const int idx = __shfl(bidx0, l, 64);
        out[1 + (wave_row0 + l) * DIM + lane] = cbs[idx * DIM + lane];
    }
    const size_t wave_row1 = (size_t)row1 - lane;
#pragma unroll 4
    for (int l = 0; l < 64; ++l) {
        const int idx = __shfl(bidx1, l, 64);
        out[1 + (wave_row1 + l) * DIM + lane] = cbs[idx * DIM + lane];
    }

    out[1 + (size_t)N_ROWS * DIM + row0] = (float)bidx0;  // coalesced
    out[1 + (size_t)N_ROWS * DIM + row1] = (float)bidx1;

    // loss contribution: sum of both rows' ||x - e||^2 (noise ~1e-5, thr ~2%)
    float lrow = best0 + best1;
#pragma unroll
    for (int off = 32; off > 0; off >>= 1) lrow += __shfl_down(lrow, off, 64);
    if (lane == 0) atomicAdd(loss_acc, lrow);
}

// ---- kernel 3: finalize loss ----
__global__ void fin_kernel(const float* __restrict__ loss_acc,
                           float* __restrict__ out) {
    if (threadIdx.x == 0) {
        float mean_sq = (*loss_acc) / (float)((size_t)N_ROWS * DIM);
        out[0] = 1.25f * mean_sq;  // q_loss + COMMITMENT_COST * e_loss
    }
}

extern "C" void kernel_launch(void* const* d_in, const int* in_sizes, int n_in,
                              void* d_out, int out_size, void* d_ws, size_t ws_size,
                              hipStream_t stream) {
    const float* x  = (const float*)d_in[0];
    const float* cb = (const float*)d_in[1];
    float* out = (float*)d_out;

    float* loss_acc = (float*)d_ws;                 // 4 B accumulator
    float* esq      = (float*)((char*)d_ws + 256);  // 512 floats

    hipMemsetAsync(d_ws, 0, 4, stream);             // zero loss accumulator
    esq_kernel<<<2, 256, 0, stream>>>(cb, esq);
    vq_kernel<<<N_ROWS / (BLK * RPT), BLK, LDS_FLOATS * sizeof(float), stream>>>(
        x, cb, esq, out, loss_acc);
    fin_kernel<<<1, 64, 0, stream>>>(loss_acc, out);
}